// Round 1
// baseline (134.010 us; speedup 1.0000x reference)
//
#include <hip/hip_runtime.h>

#define LENSZ 11
#define RAD   5
#define TS    16
#define WIN   (TS + LENSZ - 1)   // 26
#define IMG_H 1024
#define IMG_W 1024
#define HW    (IMG_H * IMG_W)

// sigmoid(4*(sd-dd)) = 1/(1+exp2(C4L2*(sd-dd))), C4L2 = -4*log2(e)
#define C4L2  (-5.770780163555854f)

__global__ __launch_bounds__(256) void scatter_render_kernel(
    const float* __restrict__ x,      // (B,4,H,W)
    const float* __restrict__ lens,   // (B,1)
    float* __restrict__ out)          // (B,3,H,W)
{
    __shared__ float4 win[WIN][WIN];

    const int b   = blockIdx.z;
    const int bx0 = blockIdx.x * TS;
    const int by0 = blockIdx.y * TS;
    const int tx  = threadIdx.x;
    const int ty  = threadIdx.y;
    const int tid = ty * TS + tx;

    const float scale = lens[b];
    const float* xb = x + (size_t)b * 4 * HW;

    // Stage 26x26 window of (r,g,b,disp) into LDS with edge clamping.
    for (int idx = tid; idx < WIN * WIN; idx += 256) {
        int wy = idx / WIN;
        int wx = idx - wy * WIN;
        int gy = by0 - RAD + wy; gy = min(max(gy, 0), IMG_H - 1);
        int gx = bx0 - RAD + wx; gx = min(max(gx, 0), IMG_W - 1);
        int base = gy * IMG_W + gx;
        float4 v;
        v.x = xb[base];
        v.y = xb[base + HW];
        v.z = xb[base + 2 * HW];
        v.w = xb[base + 3 * HW];
        win[wy][wx] = v;
    }
    __syncthreads();

    const float dd = win[ty + RAD][tx + RAD].w;   // dest disparity
    const float zd = C4L2 * dd;                   // hoisted sigmoid term

    float nr = 0.f, ng = 0.f, nb = 0.f, den = 0.f;

    // Active dx range per row of the disk (dist <= 5.5)
    constexpr int XMIN[LENSZ] = {3, 2, 1, 0, 0, 0, 0, 0, 1, 2, 3};
    constexpr int XMAX[LENSZ] = {7, 8, 9, 10, 10, 10, 10, 10, 9, 8, 7};

#pragma unroll
    for (int ky = 0; ky < LENSZ; ++ky) {
#pragma unroll
        for (int kx = XMIN[ky]; kx <= XMAX[ky]; ++kx) {
            const int dy = ky - RAD;
            const int dx = kx - RAD;
            // folded at compile time after full unroll:
            const float c0 = 0.5f - sqrtf((float)(dy * dy + dx * dx));

            float4 s = win[ty + ky][tx + kx];
            float sd  = s.w;
            float coc = scale * fabsf(sd);
            float t   = coc + c0;
            float w0  = fminf(fmaxf(t, 0.f), 1.f);          // v_med3
            float e   = __builtin_amdgcn_exp2f(C4L2 * sd - zd);
            float occ = __builtin_amdgcn_rcpf(1.f + e);     // sigmoid
            float w   = w0 * occ;
            nr = fmaf(w, s.x, nr);
            ng = fmaf(w, s.y, ng);
            nb = fmaf(w, s.z, nb);
            den += w;
        }
    }

    const float inv = __builtin_amdgcn_rcpf(den + 1e-8f);
    const size_t obase = (size_t)b * 3 * HW + (size_t)(by0 + ty) * IMG_W + (bx0 + tx);
    out[obase]          = nr * inv;
    out[obase + HW]     = ng * inv;
    out[obase + 2 * HW] = nb * inv;
}

extern "C" void kernel_launch(void* const* d_in, const int* in_sizes, int n_in,
                              void* d_out, int out_size, void* d_ws, size_t ws_size,
                              hipStream_t stream) {
    const float* x    = (const float*)d_in[0];
    const float* lens = (const float*)d_in[1];
    float* out        = (float*)d_out;

    const int B = in_sizes[1];  // lens_effects has B elements

    dim3 block(TS, TS, 1);
    dim3 grid(IMG_W / TS, IMG_H / TS, B);
    scatter_render_kernel<<<grid, block, 0, stream>>>(x, lens, out);
}